// Round 3
// baseline (679.769 us; speedup 1.0000x reference)
//
#include <hip/hip_runtime.h>

#define T_DIM 2048
#define N_DIM 256
#define K_DIM 256
#define C_DIM 40
#define CHUNK 32
#define NCHUNK 64            // T_DIM / CHUNK

#define LOG2E_F 1.44269504088896340736f
#define LN2_F   0.69314718055994530942f
#define NEGBIG  (-1.0e30f)

__device__ __forceinline__ float fexp2(float x) { return exp2f(x); }
__device__ __forceinline__ float flog2(float x) { return log2f(x); }
__device__ __forceinline__ float frcp(float x) { return __frcp_rn(x); }

// ---------------------------------------------------------------------------
// K1: y[row][c] = 5*tanh(dot(x[row], W[c]) + b[c]);  1 row per thread.
// W and b stay on the SCALAR path: uniform pointer + compile-time-constant
// index -> s_load_dwordx4/x16 through K$, costing zero VALU/DS cycles
// (round 2 put W in LDS and went DS-pipe-bound on broadcast ds_read_b128;
// round 1 spilled acc[] at default occupancy -> launch_bounds(256,4)).
// ---------------------------------------------------------------------------
__global__ __launch_bounds__(256, 4) void k1_gemm_tanh(
    const float* __restrict__ x, const float* __restrict__ W,
    const float* __restrict__ b, float* __restrict__ y)
{
    const size_t row = (size_t)blockIdx.x * 256 + threadIdx.x;
    const float4* __restrict__ xr = (const float4*)(x + row * K_DIM);

    float acc[C_DIM];
#pragma unroll
    for (int c = 0; c < C_DIM; ++c) acc[c] = b[c];

#pragma unroll 2
    for (int kt = 0; kt < 16; ++kt) {
        const float4 a0 = xr[kt * 4 + 0];
        const float4 a1 = xr[kt * 4 + 1];
        const float4 a2 = xr[kt * 4 + 2];
        const float4 a3 = xr[kt * 4 + 3];
        const float* __restrict__ wb = W + kt * 16;
#pragma unroll
        for (int c = 0; c < C_DIM; ++c) {
            const float4 w0 = *(const float4*)(wb + c * K_DIM + 0);
            const float4 w1 = *(const float4*)(wb + c * K_DIM + 4);
            const float4 w2 = *(const float4*)(wb + c * K_DIM + 8);
            const float4 w3 = *(const float4*)(wb + c * K_DIM + 12);
            float s = acc[c];
            s = fmaf(a0.x, w0.x, s); s = fmaf(a0.y, w0.y, s);
            s = fmaf(a0.z, w0.z, s); s = fmaf(a0.w, w0.w, s);
            s = fmaf(a1.x, w1.x, s); s = fmaf(a1.y, w1.y, s);
            s = fmaf(a1.z, w1.z, s); s = fmaf(a1.w, w1.w, s);
            s = fmaf(a2.x, w2.x, s); s = fmaf(a2.y, w2.y, s);
            s = fmaf(a2.z, w2.z, s); s = fmaf(a2.w, w2.w, s);
            s = fmaf(a3.x, w3.x, s); s = fmaf(a3.y, w3.y, s);
            s = fmaf(a3.z, w3.z, s); s = fmaf(a3.w, w3.w, s);
            acc[c] = s;
        }
    }

    float4* __restrict__ yo = (float4*)(y + row * C_DIM);
#pragma unroll
    for (int q = 0; q < 10; ++q) {
        float4 o;
        float* po = (float*)&o;
#pragma unroll
        for (int j = 0; j < 4; ++j) {
            const float v = acc[4 * q + j];
            const float e = fexp2(fabsf(v) * (2.0f * LOG2E_F)); // e^(2|v|)
            const float t = 1.0f - 2.0f * frcp(e + 1.0f);       // tanh(|v|)
            po[j] = 5.0f * copysignf(t, v);
        }
        yo[q] = o;
    }
}

// ---------------------------------------------------------------------------
// K2: per (chain n, chunk g) propagate the 8x8 log-semiring matrix through
// 32 steps. 8 lanes per task; lane c holds column M[:,c] -> inner loop is
// fully lane-local. Base-2 domain (scores pre-scaled by log2(e)).
// ---------------------------------------------------------------------------
__global__ __launch_bounds__(256) void k2_chunks(
    const float* __restrict__ y, float* __restrict__ cmat)
{
    const int tid  = threadIdx.x;
    const int wave = tid >> 6;
    const int lane = tid & 63;
    const int task = lane >> 3;   // 8 tasks per wave
    const int c    = lane & 7;    // column owned by this lane
    const int g    = blockIdx.x & (NCHUNK - 1);
    const int n    = ((blockIdx.x >> 6) << 5) + (wave << 3) + task;

    float col[8];
#pragma unroll
    for (int j = 0; j < 8; ++j) col[j] = (j == c) ? 0.0f : NEGBIG;

    const float* __restrict__ yp =
        y + ((size_t)(g * CHUNK) * N_DIM + (size_t)n) * C_DIM;

#pragma unroll 1
    for (int s = 0; s < CHUNK; ++s) {
        float sc[C_DIM];
        const float4* p4 = (const float4*)yp;
#pragma unroll
        for (int q = 0; q < 10; ++q) {
            const float4 v = p4[q];
            sc[4 * q + 0] = v.x * LOG2E_F;
            sc[4 * q + 1] = v.y * LOG2E_F;
            sc[4 * q + 2] = v.z * LOG2E_F;
            sc[4 * q + 3] = v.w * LOG2E_F;
        }
        float nc[8];
#pragma unroll
        for (int d = 0; d < 4; ++d) {          // dense rows: lse over 8
            float tv[8];
#pragma unroll
            for (int j = 0; j < 8; ++j) tv[j] = sc[d * 8 + j] + col[j];
            float m = tv[0];
#pragma unroll
            for (int j = 1; j < 8; ++j) m = fmaxf(m, tv[j]);
            float ss = 0.0f;
#pragma unroll
            for (int j = 0; j < 8; ++j) ss += fexp2(tv[j] - m);
            nc[d] = m + flog2(ss);
        }
#pragma unroll
        for (int i = 0; i < 4; ++i) {          // sparse rows: logaddexp of 2
            const float a  = sc[32 + i] + col[i];
            const float bb = sc[36 + i] + col[i + 4];
            const float m  = fmaxf(a, bb);
            const float ss = fexp2(a - m) + fexp2(bb - m);
            nc[4 + i] = m + flog2(ss);
        }
#pragma unroll
        for (int j = 0; j < 8; ++j) col[j] = nc[j];
        yp += (size_t)N_DIM * C_DIM;
    }
    // store M[j][c] at cmat[((g*8 + c)*N_DIM + n)*8 + j]  (contig 8 per lane)
    float* __restrict__ op = cmat + (((size_t)g * 8 + c) * N_DIM + n) * 8;
#pragma unroll
    for (int j = 0; j < 8; ++j) op[j] = col[j];
}

// ---------------------------------------------------------------------------
// K3: per chain, fold the 64 chunk matrices into logZ via log-semiring
// mat-vec on an 8-vector starting at 0.
// ---------------------------------------------------------------------------
__global__ __launch_bounds__(256) void k3_combine(
    const float* __restrict__ cmat, float* __restrict__ corr)
{
    const int tid = threadIdx.x;
    const int d   = tid & 7;
    const int n   = blockIdx.x * 32 + (tid >> 3);

    float v[8];
#pragma unroll
    for (int j = 0; j < 8; ++j) v[j] = 0.0f;

#pragma unroll 1
    for (int g = 0; g < NCHUNK; ++g) {
        const float* mg = cmat + ((size_t)g * 8 * N_DIM + n) * 8 + d;
        float mm[8];
#pragma unroll
        for (int j = 0; j < 8; ++j) mm[j] = mg[(size_t)j * N_DIM * 8];
        float tv[8];
#pragma unroll
        for (int j = 0; j < 8; ++j) tv[j] = mm[j] + v[j];
        float m = tv[0];
#pragma unroll
        for (int j = 1; j < 8; ++j) m = fmaxf(m, tv[j]);
        float ss = 0.0f;
#pragma unroll
        for (int j = 0; j < 8; ++j) ss += fexp2(tv[j] - m);
        const float nv = m + flog2(ss);
#pragma unroll
        for (int j = 0; j < 8; ++j) v[j] = __shfl(nv, j, 8);
    }
    float m = v[0];
#pragma unroll
    for (int j = 1; j < 8; ++j) m = fmaxf(m, v[j]);
    float ss = 0.0f;
#pragma unroll
    for (int j = 0; j < 8; ++j) ss += fexp2(v[j] - m);
    const float lz2 = m + flog2(ss);                 // base-2 logZ
    if (d == 0) corr[n] = lz2 * LN2_F / (float)T_DIM;
}

// ---------------------------------------------------------------------------
// K4: out[t][n][c] = y[t][n][c] - corr[n]
// ---------------------------------------------------------------------------
__global__ __launch_bounds__(256) void k4_final(
    float* __restrict__ out, const float* __restrict__ corr)
{
    const unsigned int i = blockIdx.x * 256u + threadIdx.x;  // float4 index
    float4* o4 = (float4*)out;
    float4 v = o4[i];
    const unsigned int n = (i / 10u) & (N_DIM - 1);          // 10 float4 / row
    const float cr = corr[n];
    v.x -= cr; v.y -= cr; v.z -= cr; v.w -= cr;
    o4[i] = v;
}

// ---------------------------------------------------------------------------
extern "C" void kernel_launch(void* const* d_in, const int* in_sizes, int n_in,
                              void* d_out, int out_size, void* d_ws, size_t ws_size,
                              hipStream_t stream)
{
    const float* x = (const float*)d_in[0];
    const float* W = (const float*)d_in[1];
    const float* b = (const float*)d_in[2];
    float* y = (float*)d_out;

    float* cmat = (float*)d_ws;                               // 64*8*256*8 f32 = 4 MB
    float* corr = (float*)d_ws + (size_t)NCHUNK * 8 * N_DIM * 8;

    hipLaunchKernelGGL(k1_gemm_tanh, dim3(2048), dim3(256), 0, stream, x, W, b, y);
    hipLaunchKernelGGL(k2_chunks,    dim3(512),  dim3(256), 0, stream, y, cmat);
    hipLaunchKernelGGL(k3_combine,   dim3(8),    dim3(256), 0, stream, cmat, corr);
    hipLaunchKernelGGL(k4_final,     dim3((T_DIM * N_DIM * C_DIM / 4) / 256),
                       dim3(256), 0, stream, y, corr);
}

// Round 4
// 409.929 us; speedup vs baseline: 1.6583x; 1.6583x over previous
//
#include <hip/hip_runtime.h>

#define T_DIM 2048
#define N_DIM 256
#define K_DIM 256
#define C_DIM 40
#define CHUNK 32
#define NCHUNK 64            // T_DIM / CHUNK

#define ROWS_PER_BLK 128
#define KCHUNK 64
#define LPAD 68              // floats per LDS row: 272B, 16B-aligned, quad=(row+k4)%8

#define LOG2E_F 1.44269504088896340736f
#define LN2_F   0.69314718055994530942f
#define NEGBIG  (-1.0e30f)

__device__ __forceinline__ float fexp2(float x) { return exp2f(x); }
__device__ __forceinline__ float flog2(float x) { return log2f(x); }
__device__ __forceinline__ float frcp(float x) { return __frcp_rn(x); }

// ---------------------------------------------------------------------------
// K1: y[row][c] = 5*tanh(dot(x[row], W[c]) + b[c])
// Tiled: block = 128 rows x 40 cols, 4 waves = {2 row-halves} x {2 c-groups
// of 20}. acc[20]/thread (rounds 1-3 proved hipcc spills acc[40] no matter
// the launch bounds: WRITE_SIZE 276MB vs 83MB ideal). x staged in LDS with
// coalesced float4 loads; W/b on the scalar path (readfirstlane-uniform
// c-group -> s_load_dwordx4 via K$: zero VALU/DS/VMEM cost).
// ---------------------------------------------------------------------------
__global__ __launch_bounds__(256, 4) void k1_gemm_tanh(
    const float* __restrict__ x, const float* __restrict__ W,
    const float* __restrict__ b, float* __restrict__ y)
{
    __shared__ __align__(16) float xs[ROWS_PER_BLK * LPAD];   // 34.8 KB

    const int tid  = threadIdx.x;
    const int wave = __builtin_amdgcn_readfirstlane(tid >> 6); // SGPR, uniform
    const int lane = tid & 63;
    const int cg   = wave & 1;        // c-group: outputs [cg*20, cg*20+20)
    const int rh   = wave >> 1;       // row half
    const int row  = rh * 64 + lane;  // row within block tile, 0..127
    const size_t grow = (size_t)blockIdx.x * ROWS_PER_BLK;

    const float* __restrict__ Wc = W + (size_t)cg * 20 * K_DIM; // uniform
    const float* __restrict__ bc = b + cg * 20;                 // uniform

    float acc[20];
#pragma unroll
    for (int c = 0; c < 20; ++c) acc[c] = bc[c];

#pragma unroll 1
    for (int ch = 0; ch < 4; ++ch) {
        __syncthreads();
        // stage 128 rows x 64 floats: 2048 float4 / 256 threads = 8 each,
        // 16 consecutive threads cover one row-chunk (256B) -> coalesced.
#pragma unroll
        for (int p = 0; p < 8; ++p) {
            const int f4 = p * 256 + tid;
            const int r  = f4 >> 4;
            const int kq = f4 & 15;
            const float4 v = *(const float4*)(
                x + (grow + r) * K_DIM + ch * KCHUNK + kq * 4);
            *(float4*)(xs + r * LPAD + kq * 4) = v;  // ds_write_b128
        }
        __syncthreads();

#pragma unroll 2
        for (int k4 = 0; k4 < 16; ++k4) {
            const float4 xa = *(const float4*)(xs + row * LPAD + k4 * 4);
            const float* __restrict__ wk = Wc + ch * KCHUNK + k4 * 4;
#pragma unroll
            for (int c = 0; c < 20; ++c) {
                const float4 w = *(const float4*)(wk + (size_t)c * K_DIM);
                float s = acc[c];
                s = fmaf(xa.x, w.x, s); s = fmaf(xa.y, w.y, s);
                s = fmaf(xa.z, w.z, s); s = fmaf(xa.w, w.w, s);
                acc[c] = s;
            }
        }
    }

    // epilogue: 5*tanh, write 20 floats at y[row][cg*20 .. cg*20+20)
    float* __restrict__ yo = y + (grow + row) * C_DIM + cg * 20;
#pragma unroll
    for (int q = 0; q < 5; ++q) {
        float4 o;
        float* po = (float*)&o;
#pragma unroll
        for (int j = 0; j < 4; ++j) {
            const float v = acc[4 * q + j];
            const float e = fexp2(fabsf(v) * (2.0f * LOG2E_F)); // e^(2|v|)
            const float t = 1.0f - 2.0f * frcp(e + 1.0f);       // tanh(|v|)
            po[j] = 5.0f * copysignf(t, v);
        }
        *(float4*)(yo + 4 * q) = o;
    }
}

// ---------------------------------------------------------------------------
// K2: per (chain n, chunk g) propagate the 8x8 log-semiring matrix through
// 32 steps. 8 lanes per task; lane c holds column M[:,c] -> inner loop is
// fully lane-local. Base-2 domain (scores pre-scaled by log2(e)).
// ---------------------------------------------------------------------------
__global__ __launch_bounds__(256) void k2_chunks(
    const float* __restrict__ y, float* __restrict__ cmat)
{
    const int tid  = threadIdx.x;
    const int wave = tid >> 6;
    const int lane = tid & 63;
    const int task = lane >> 3;   // 8 tasks per wave
    const int c    = lane & 7;    // column owned by this lane
    const int g    = blockIdx.x & (NCHUNK - 1);
    const int n    = ((blockIdx.x >> 6) << 5) + (wave << 3) + task;

    float col[8];
#pragma unroll
    for (int j = 0; j < 8; ++j) col[j] = (j == c) ? 0.0f : NEGBIG;

    const float* __restrict__ yp =
        y + ((size_t)(g * CHUNK) * N_DIM + (size_t)n) * C_DIM;

#pragma unroll 1
    for (int s = 0; s < CHUNK; ++s) {
        float sc[C_DIM];
        const float4* p4 = (const float4*)yp;
#pragma unroll
        for (int q = 0; q < 10; ++q) {
            const float4 v = p4[q];
            sc[4 * q + 0] = v.x * LOG2E_F;
            sc[4 * q + 1] = v.y * LOG2E_F;
            sc[4 * q + 2] = v.z * LOG2E_F;
            sc[4 * q + 3] = v.w * LOG2E_F;
        }
        float nc[8];
#pragma unroll
        for (int d = 0; d < 4; ++d) {          // dense rows: lse over 8
            float tv[8];
#pragma unroll
            for (int j = 0; j < 8; ++j) tv[j] = sc[d * 8 + j] + col[j];
            float m = tv[0];
#pragma unroll
            for (int j = 1; j < 8; ++j) m = fmaxf(m, tv[j]);
            float ss = 0.0f;
#pragma unroll
            for (int j = 0; j < 8; ++j) ss += fexp2(tv[j] - m);
            nc[d] = m + flog2(ss);
        }
#pragma unroll
        for (int i = 0; i < 4; ++i) {          // sparse rows: logaddexp of 2
            const float a  = sc[32 + i] + col[i];
            const float bb = sc[36 + i] + col[i + 4];
            const float m  = fmaxf(a, bb);
            const float ss = fexp2(a - m) + fexp2(bb - m);
            nc[4 + i] = m + flog2(ss);
        }
#pragma unroll
        for (int j = 0; j < 8; ++j) col[j] = nc[j];
        yp += (size_t)N_DIM * C_DIM;
    }
    // store M[j][c] at cmat[((g*8 + c)*N_DIM + n)*8 + j]  (contig 8 per lane)
    float* __restrict__ op = cmat + (((size_t)g * 8 + c) * N_DIM + n) * 8;
#pragma unroll
    for (int j = 0; j < 8; ++j) op[j] = col[j];
}

// ---------------------------------------------------------------------------
// K3: per chain, fold the 64 chunk matrices into logZ via log-semiring
// mat-vec on an 8-vector starting at 0.
// ---------------------------------------------------------------------------
__global__ __launch_bounds__(256) void k3_combine(
    const float* __restrict__ cmat, float* __restrict__ corr)
{
    const int tid = threadIdx.x;
    const int d   = tid & 7;
    const int n   = blockIdx.x * 32 + (tid >> 3);

    float v[8];
#pragma unroll
    for (int j = 0; j < 8; ++j) v[j] = 0.0f;

#pragma unroll 1
    for (int g = 0; g < NCHUNK; ++g) {
        const float* mg = cmat + ((size_t)g * 8 * N_DIM + n) * 8 + d;
        float mm[8];
#pragma unroll
        for (int j = 0; j < 8; ++j) mm[j] = mg[(size_t)j * N_DIM * 8];
        float tv[8];
#pragma unroll
        for (int j = 0; j < 8; ++j) tv[j] = mm[j] + v[j];
        float m = tv[0];
#pragma unroll
        for (int j = 1; j < 8; ++j) m = fmaxf(m, tv[j]);
        float ss = 0.0f;
#pragma unroll
        for (int j = 0; j < 8; ++j) ss += fexp2(tv[j] - m);
        const float nv = m + flog2(ss);
#pragma unroll
        for (int j = 0; j < 8; ++j) v[j] = __shfl(nv, j, 8);
    }
    float m = v[0];
#pragma unroll
    for (int j = 1; j < 8; ++j) m = fmaxf(m, v[j]);
    float ss = 0.0f;
#pragma unroll
    for (int j = 0; j < 8; ++j) ss += fexp2(v[j] - m);
    const float lz2 = m + flog2(ss);                 // base-2 logZ
    if (d == 0) corr[n] = lz2 * LN2_F / (float)T_DIM;
}

// ---------------------------------------------------------------------------
// K4: out[t][n][c] = y[t][n][c] - corr[n]
// ---------------------------------------------------------------------------
__global__ __launch_bounds__(256) void k4_final(
    float* __restrict__ out, const float* __restrict__ corr)
{
    const unsigned int i = blockIdx.x * 256u + threadIdx.x;  // float4 index
    float4* o4 = (float4*)out;
    float4 v = o4[i];
    const unsigned int n = (i / 10u) & (N_DIM - 1);          // 10 float4 / row
    const float cr = corr[n];
    v.x -= cr; v.y -= cr; v.z -= cr; v.w -= cr;
    o4[i] = v;
}

// ---------------------------------------------------------------------------
extern "C" void kernel_launch(void* const* d_in, const int* in_sizes, int n_in,
                              void* d_out, int out_size, void* d_ws, size_t ws_size,
                              hipStream_t stream)
{
    const float* x = (const float*)d_in[0];
    const float* W = (const float*)d_in[1];
    const float* b = (const float*)d_in[2];
    float* y = (float*)d_out;

    float* cmat = (float*)d_ws;                               // 64*8*256*8 f32 = 4 MB
    float* corr = (float*)d_ws + (size_t)NCHUNK * 8 * N_DIM * 8;

    hipLaunchKernelGGL(k1_gemm_tanh, dim3((T_DIM * N_DIM) / ROWS_PER_BLK),
                       dim3(256), 0, stream, x, W, b, y);
    hipLaunchKernelGGL(k2_chunks,    dim3(512),  dim3(256), 0, stream, y, cmat);
    hipLaunchKernelGGL(k3_combine,   dim3(8),    dim3(256), 0, stream, cmat, corr);
    hipLaunchKernelGGL(k4_final,     dim3((T_DIM * N_DIM * C_DIM / 4) / 256),
                       dim3(256), 0, stream, y, corr);
}

// Round 5
// 301.186 us; speedup vs baseline: 2.2570x; 1.3610x over previous
//
#include <hip/hip_runtime.h>

#define T_DIM 2048
#define N_DIM 256
#define K_DIM 256
#define C_DIM 40
#define CHUNK 32
#define NCHUNK 64            // T_DIM / CHUNK
#define NTILES (T_DIM * N_DIM / 16)   // 32768 M-tiles of 16 rows

#define LOG2E_F 1.44269504088896340736f
#define LN2_F   0.69314718055994530942f
#define NEGBIG  (-1.0e30f)

typedef short bf16x8 __attribute__((ext_vector_type(8)));
typedef float f32x4  __attribute__((ext_vector_type(4)));
typedef unsigned int u32x4 __attribute__((ext_vector_type(4)));

__device__ __forceinline__ float fexp2(float x) { return exp2f(x); }
__device__ __forceinline__ float flog2(float x) { return log2f(x); }
__device__ __forceinline__ float frcp(float x) { return __frcp_rn(x); }

// pack two fp32 -> one u32 of two bf16 (RNE)
__device__ __forceinline__ unsigned int pkbf(float lo, float hi)
{
    unsigned int a = __float_as_uint(lo);
    unsigned int b = __float_as_uint(hi);
    a += 0x7fffu + ((a >> 16) & 1u);
    b += 0x7fffu + ((b >> 16) & 1u);
    return (a >> 16) | (b & 0xffff0000u);
}

__device__ __forceinline__ bf16x8 pack8(float4 lo, float4 hi)
{
    u32x4 t;
    t[0] = pkbf(lo.x, lo.y);
    t[1] = pkbf(lo.z, lo.w);
    t[2] = pkbf(hi.x, hi.y);
    t[3] = pkbf(hi.z, hi.w);
    return __builtin_bit_cast(bf16x8, t);
}

__device__ __forceinline__ float tanh5(float v)
{
    const float e = fexp2(fabsf(v) * (2.0f * LOG2E_F)); // e^(2|v|)
    const float t = 1.0f - 2.0f * frcp(e + 1.0f);       // tanh(|v|)
    return 5.0f * copysignf(t, v);
}

// ---------------------------------------------------------------------------
// K1: y[row][c] = 5*tanh(dot(x[row], W[c]) + b[c])  via bf16 MFMA.
// Per wave: all of W (40 cols padded to 48 = 3 n-tiles) lives in VGPRs as
// B-fragments (96 VGPR), converted once; grid-stride over 16-row M-tiles.
// No LDS / no SMEM in the hot loop (rounds 2-4: DS-bound, then lgkmcnt-
// latency-bound on s_load W delivery). mfma_f32_16x16x32_bf16 layout:
// A/B: idx = lane&15, k = (lane>>4)*8 + i; C/D: col=lane&15,
// row=(lane>>4)*4+reg  (guide §3, m89/m92-verified).
// ---------------------------------------------------------------------------
__global__ __launch_bounds__(256, 3) void k1_gemm_tanh(
    const float* __restrict__ x, const float* __restrict__ W,
    const float* __restrict__ b, float* __restrict__ y)
{
    const int tid  = threadIdx.x;
    const int wave = tid >> 6;
    const int lane = tid & 63;
    const int lr   = lane & 15;   // A-row / B-col / D-col selector
    const int kg   = lane >> 4;   // k-group 0..3

    // ---- convert W -> B-fragments (once per wave) ----
    bf16x8 wf[3][8];
    float  bv[3];
#pragma unroll
    for (int nt = 0; nt < 3; ++nt) {
        const int c = nt * 16 + lr;
        const bool valid = (c < C_DIM);
        const float* __restrict__ wp =
            W + (size_t)(valid ? c : 0) * K_DIM + kg * 8;
        bv[nt] = valid ? b[c] : 0.0f;
#pragma unroll
        for (int ks = 0; ks < 8; ++ks) {
            float4 lo = *(const float4*)(wp + ks * 32);
            float4 hi = *(const float4*)(wp + ks * 32 + 4);
            if (!valid) { lo = make_float4(0, 0, 0, 0); hi = lo; }
            wf[nt][ks] = pack8(lo, hi);
        }
    }

    const int wid    = blockIdx.x * 4 + wave;
    const int nwaves = gridDim.x * 4;

    for (int tile = wid; tile < NTILES; tile += nwaves) {
        const float* __restrict__ xp =
            x + ((size_t)tile * 16 + lr) * K_DIM + kg * 8;

        f32x4 af[3];
#pragma unroll
        for (int nt = 0; nt < 3; ++nt) {
            af[nt][0] = bv[nt]; af[nt][1] = bv[nt];
            af[nt][2] = bv[nt]; af[nt][3] = bv[nt];
        }

#pragma unroll
        for (int ks = 0; ks < 8; ++ks) {
            const float4 lo = *(const float4*)(xp + ks * 32);
            const float4 hi = *(const float4*)(xp + ks * 32 + 4);
            const bf16x8 a = pack8(lo, hi);
            af[0] = __builtin_amdgcn_mfma_f32_16x16x32_bf16(a, wf[0][ks], af[0], 0, 0, 0);
            af[1] = __builtin_amdgcn_mfma_f32_16x16x32_bf16(a, wf[1][ks], af[1], 0, 0, 0);
            af[2] = __builtin_amdgcn_mfma_f32_16x16x32_bf16(a, wf[2][ks], af[2], 0, 0, 0);
        }

        // epilogue: D[row][col], row = kg*4+r, col = nt*16+lr
        float* __restrict__ yrow =
            y + ((size_t)tile * 16 + kg * 4) * C_DIM;
#pragma unroll
        for (int nt = 0; nt < 3; ++nt) {
            const int col = nt * 16 + lr;
            if (col < C_DIM) {
#pragma unroll
                for (int r = 0; r < 4; ++r)
                    yrow[r * C_DIM + col] = tanh5(af[nt][r]);
            }
        }
    }
}

// ---------------------------------------------------------------------------
// K2: per (chain n, chunk g) propagate the 8x8 log-semiring matrix through
// 32 steps. 8 lanes per task; lane c holds column M[:,c] -> inner loop is
// fully lane-local. Base-2 domain (scores pre-scaled by log2(e)).
// ---------------------------------------------------------------------------
__global__ __launch_bounds__(256) void k2_chunks(
    const float* __restrict__ y, float* __restrict__ cmat)
{
    const int tid  = threadIdx.x;
    const int wave = tid >> 6;
    const int lane = tid & 63;
    const int task = lane >> 3;   // 8 tasks per wave
    const int c    = lane & 7;    // column owned by this lane
    const int g    = blockIdx.x & (NCHUNK - 1);
    const int n    = ((blockIdx.x >> 6) << 5) + (wave << 3) + task;

    float col[8];
#pragma unroll
    for (int j = 0; j < 8; ++j) col[j] = (j == c) ? 0.0f : NEGBIG;

    const float* __restrict__ yp =
        y + ((size_t)(g * CHUNK) * N_DIM + (size_t)n) * C_DIM;

#pragma unroll 1
    for (int s = 0; s < CHUNK; ++s) {
        float sc[C_DIM];
        const float4* p4 = (const float4*)yp;
#pragma unroll
        for (int q = 0; q < 10; ++q) {
            const float4 v = p4[q];
            sc[4 * q + 0] = v.x * LOG2E_F;
            sc[4 * q + 1] = v.y * LOG2E_F;
            sc[4 * q + 2] = v.z * LOG2E_F;
            sc[4 * q + 3] = v.w * LOG2E_F;
        }
        float nc[8];
#pragma unroll
        for (int d = 0; d < 4; ++d) {          // dense rows: lse over 8
            float tv[8];
#pragma unroll
            for (int j = 0; j < 8; ++j) tv[j] = sc[d * 8 + j] + col[j];
            float m = tv[0];
#pragma unroll
            for (int j = 1; j < 8; ++j) m = fmaxf(m, tv[j]);
            float ss = 0.0f;
#pragma unroll
            for (int j = 0; j < 8; ++j) ss += fexp2(tv[j] - m);
            nc[d] = m + flog2(ss);
        }
#pragma unroll
        for (int i = 0; i < 4; ++i) {          // sparse rows: logaddexp of 2
            const float a  = sc[32 + i] + col[i];
            const float bb = sc[36 + i] + col[i + 4];
            const float m  = fmaxf(a, bb);
            const float ss = fexp2(a - m) + fexp2(bb - m);
            nc[4 + i] = m + flog2(ss);
        }
#pragma unroll
        for (int j = 0; j < 8; ++j) col[j] = nc[j];
        yp += (size_t)N_DIM * C_DIM;
    }
    // store M[j][c] at cmat[((g*8 + c)*N_DIM + n)*8 + j]  (contig 8 per lane)
    float* __restrict__ op = cmat + (((size_t)g * 8 + c) * N_DIM + n) * 8;
#pragma unroll
    for (int j = 0; j < 8; ++j) op[j] = col[j];
}

// ---------------------------------------------------------------------------
// K3: per chain, fold the 64 chunk matrices into logZ via log-semiring
// mat-vec on an 8-vector starting at 0.
// ---------------------------------------------------------------------------
__global__ __launch_bounds__(256) void k3_combine(
    const float* __restrict__ cmat, float* __restrict__ corr)
{
    const int tid = threadIdx.x;
    const int d   = tid & 7;
    const int n   = blockIdx.x * 32 + (tid >> 3);

    float v[8];
#pragma unroll
    for (int j = 0; j < 8; ++j) v[j] = 0.0f;

#pragma unroll 1
    for (int g = 0; g < NCHUNK; ++g) {
        const float* mg = cmat + ((size_t)g * 8 * N_DIM + n) * 8 + d;
        float mm[8];
#pragma unroll
        for (int j = 0; j < 8; ++j) mm[j] = mg[(size_t)j * N_DIM * 8];
        float tv[8];
#pragma unroll
        for (int j = 0; j < 8; ++j) tv[j] = mm[j] + v[j];
        float m = tv[0];
#pragma unroll
        for (int j = 1; j < 8; ++j) m = fmaxf(m, tv[j]);
        float ss = 0.0f;
#pragma unroll
        for (int j = 0; j < 8; ++j) ss += fexp2(tv[j] - m);
        const float nv = m + flog2(ss);
#pragma unroll
        for (int j = 0; j < 8; ++j) v[j] = __shfl(nv, j, 8);
    }
    float m = v[0];
#pragma unroll
    for (int j = 1; j < 8; ++j) m = fmaxf(m, v[j]);
    float ss = 0.0f;
#pragma unroll
    for (int j = 0; j < 8; ++j) ss += fexp2(v[j] - m);
    const float lz2 = m + flog2(ss);                 // base-2 logZ
    if (d == 0) corr[n] = lz2 * LN2_F / (float)T_DIM;
}

// ---------------------------------------------------------------------------
// K4: out[t][n][c] = y[t][n][c] - corr[n]
// ---------------------------------------------------------------------------
__global__ __launch_bounds__(256) void k4_final(
    float* __restrict__ out, const float* __restrict__ corr)
{
    const unsigned int i = blockIdx.x * 256u + threadIdx.x;  // float4 index
    float4* o4 = (float4*)out;
    float4 v = o4[i];
    const unsigned int n = (i / 10u) & (N_DIM - 1);          // 10 float4 / row
    const float cr = corr[n];
    v.x -= cr; v.y -= cr; v.z -= cr; v.w -= cr;
    o4[i] = v;
}

// ---------------------------------------------------------------------------
extern "C" void kernel_launch(void* const* d_in, const int* in_sizes, int n_in,
                              void* d_out, int out_size, void* d_ws, size_t ws_size,
                              hipStream_t stream)
{
    const float* x = (const float*)d_in[0];
    const float* W = (const float*)d_in[1];
    const float* b = (const float*)d_in[2];
    float* y = (float*)d_out;

    float* cmat = (float*)d_ws;                               // 64*8*256*8 f32 = 4 MB
    float* corr = (float*)d_ws + (size_t)NCHUNK * 8 * N_DIM * 8;

    hipLaunchKernelGGL(k1_gemm_tanh, dim3(1024), dim3(256), 0, stream, x, W, b, y);
    hipLaunchKernelGGL(k2_chunks,    dim3(512),  dim3(256), 0, stream, y, cmat);
    hipLaunchKernelGGL(k3_combine,   dim3(8),    dim3(256), 0, stream, cmat, corr);
    hipLaunchKernelGGL(k4_final,     dim3((T_DIM * N_DIM * C_DIM / 4) / 256),
                       dim3(256), 0, stream, y, corr);
}

// Round 7
// 262.146 us; speedup vs baseline: 2.5931x; 1.1489x over previous
//
#include <hip/hip_runtime.h>
#include <hip/hip_bf16.h>

#define T_DIM 2048
#define N_DIM 256
#define K_DIM 256
#define C_DIM 40
#define CHUNK 32
#define NCHUNK 64            // T_DIM / CHUNK
#define NTILES (T_DIM * N_DIM / 16)   // 32768 M-tiles of 16 rows

#define LOG2E_F 1.44269504088896340736f
#define LN2_F   0.69314718055994530942f
#define NEGBIG  (-1.0e30f)

typedef short bf16x8 __attribute__((ext_vector_type(8)));
typedef float f32x4  __attribute__((ext_vector_type(4)));

__device__ __forceinline__ float fexp2(float x) { return exp2f(x); }
__device__ __forceinline__ float flog2(float x) { return log2f(x); }
__device__ __forceinline__ float frcp(float x) { return __frcp_rn(x); }

// two fp32 -> one u32 of two bf16 (compiler emits v_cvt_pk_bf16_f32; m240:
// scalar casts beat hand-written packs). memcpy not bit_cast:
// __hip_bfloat162 is not trivially copyable on this ROCm.
__device__ __forceinline__ unsigned int pk2(float a, float b)
{
    __hip_bfloat162 h = __float22bfloat162_rn(make_float2(a, b));
    unsigned int r;
    __builtin_memcpy(&r, &h, sizeof(r));
    return r;
}

__device__ __forceinline__ uint4 pack8u(float4 lo, float4 hi)
{
    uint4 t;
    t.x = pk2(lo.x, lo.y);
    t.y = pk2(lo.z, lo.w);
    t.z = pk2(hi.x, hi.y);
    t.w = pk2(hi.z, hi.w);
    return t;
}

__device__ __forceinline__ bf16x8 as_bf16x8(uint4 u)
{
    bf16x8 r;
    __builtin_memcpy(&r, &u, sizeof(r));
    return r;
}

__device__ __forceinline__ float tanh5(float v)
{
    const float e = fexp2(fabsf(v) * (2.0f * LOG2E_F)); // e^(2|v|)
    const float t = 1.0f - 2.0f * frcp(e + 1.0f);       // tanh(|v|)
    return 5.0f * copysignf(t, v);
}

// ---------------------------------------------------------------------------
// K1: y[row][c] = 5*tanh(dot(x[row], W[c]) + b[c])  via bf16 MFMA.
// W pre-packed ONCE per block into LDS as ready B-fragments (24 KB,
// lane*16B layout -> conflict-free ds_read_b128). Round-5 held W in 96
// VGPRs/lane -> 3 waves/SIMD + load-hoist starvation = 2 TB/s only.
// Now: ~30 persistent VGPRs, launch_bounds(256,4), 16 waves/CU, all 16
// x-loads of a tile in flight. mfma_f32_16x16x32_bf16 layout (m89/m92):
// A/B: idx=lane&15, k=(lane>>4)*8+i; C/D: col=lane&15, row=(lane>>4)*4+reg.
// ---------------------------------------------------------------------------
__global__ __launch_bounds__(256, 4) void k1_gemm_tanh(
    const float* __restrict__ x, const float* __restrict__ W,
    const float* __restrict__ b, float* __restrict__ y)
{
    __shared__ __align__(16) uint4 wlds[24 * 64];   // 24.5 KB: frag=(ks*3+nt)
    __shared__ float blds[48];

    const int tid = threadIdx.x;

    // ---- cooperative W->fragment build (once per block) ----
#pragma unroll
    for (int p = 0; p < 6; ++p) {
        const int f    = p * 256 + tid;   // 0..1535 lane-fragments
        const int l    = f & 63;
        const int frag = f >> 6;          // 0..23
        const int nt   = frag % 3;
        const int ks   = frag / 3;
        const int col  = nt * 16 + (l & 15);
        const int kb   = ks * 32 + (l >> 4) * 8;
        float4 lo = make_float4(0, 0, 0, 0), hi = lo;
        if (col < C_DIM) {
            lo = *(const float4*)(W + (size_t)col * K_DIM + kb);
            hi = *(const float4*)(W + (size_t)col * K_DIM + kb + 4);
        }
        wlds[frag * 64 + l] = pack8u(lo, hi);
    }
    if (tid < 48) blds[tid] = (tid < C_DIM) ? b[tid] : 0.0f;
    __syncthreads();

    const int wave = tid >> 6;
    const int lane = tid & 63;
    const int lr   = lane & 15;   // A-row / B-col / D-col selector
    const int kg   = lane >> 4;   // k-group 0..3

    const float bc0 = blds[lr];
    const float bc1 = blds[16 + lr];
    const float bc2 = blds[32 + lr];

    const int wid = blockIdx.x * 4 + wave;          // 0..4095, all resident

#pragma unroll 1
    for (int tile = wid; tile < NTILES; tile += 4096) {
        const float* __restrict__ xp =
            x + ((size_t)tile * 16 + lr) * K_DIM + kg * 8;

        f32x4 af0 = {bc0, bc0, bc0, bc0};
        f32x4 af1 = {bc1, bc1, bc1, bc1};
        f32x4 af2 = {bc2, bc2, bc2, bc2};

#pragma unroll
        for (int ks = 0; ks < 8; ++ks) {
            const float4 lo = *(const float4*)(xp + ks * 32);
            const float4 hi = *(const float4*)(xp + ks * 32 + 4);
            const bf16x8 a = as_bf16x8(pack8u(lo, hi));
            const bf16x8 w0 = *(const bf16x8*)&wlds[(ks * 3 + 0) * 64 + lane];
            const bf16x8 w1 = *(const bf16x8*)&wlds[(ks * 3 + 1) * 64 + lane];
            const bf16x8 w2 = *(const bf16x8*)&wlds[(ks * 3 + 2) * 64 + lane];
            af0 = __builtin_amdgcn_mfma_f32_16x16x32_bf16(a, w0, af0, 0, 0, 0);
            af1 = __builtin_amdgcn_mfma_f32_16x16x32_bf16(a, w1, af1, 0, 0, 0);
            af2 = __builtin_amdgcn_mfma_f32_16x16x32_bf16(a, w2, af2, 0, 0, 0);
        }

        // epilogue: D[row][col], row = kg*4+r, col = nt*16+lr
        float* __restrict__ yrow = y + ((size_t)tile * 16 + kg * 4) * C_DIM;
#pragma unroll
        for (int r = 0; r < 4; ++r) {
            yrow[r * C_DIM + lr]      = tanh5(af0[r]);
            yrow[r * C_DIM + 16 + lr] = tanh5(af1[r]);
            if (lr < 8)
                yrow[r * C_DIM + 32 + lr] = tanh5(af2[r]);
        }
    }
}

// ---------------------------------------------------------------------------
// K2: per (chain n, chunk g) propagate the 8x8 log-semiring matrix through
// 32 steps. 8 lanes per task; lane c holds column M[:,c] -> inner loop is
// fully lane-local. Base-2 domain (scores pre-scaled by log2(e)).
// ---------------------------------------------------------------------------
__global__ __launch_bounds__(256) void k2_chunks(
    const float* __restrict__ y, float* __restrict__ cmat)
{
    const int tid  = threadIdx.x;
    const int wave = tid >> 6;
    const int lane = tid & 63;
    const int task = lane >> 3;   // 8 tasks per wave
    const int c    = lane & 7;    // column owned by this lane
    const int g    = blockIdx.x & (NCHUNK - 1);
    const int n    = ((blockIdx.x >> 6) << 5) + (wave << 3) + task;

    float col[8];
#pragma unroll
    for (int j = 0; j < 8; ++j) col[j] = (j == c) ? 0.0f : NEGBIG;

    const float* __restrict__ yp =
        y + ((size_t)(g * CHUNK) * N_DIM + (size_t)n) * C_DIM;

#pragma unroll 1
    for (int s = 0; s < CHUNK; ++s) {
        float sc[C_DIM];
        const float4* p4 = (const float4*)yp;
#pragma unroll
        for (int q = 0; q < 10; ++q) {
            const float4 v = p4[q];
            sc[4 * q + 0] = v.x * LOG2E_F;
            sc[4 * q + 1] = v.y * LOG2E_F;
            sc[4 * q + 2] = v.z * LOG2E_F;
            sc[4 * q + 3] = v.w * LOG2E_F;
        }
        float nc[8];
#pragma unroll
        for (int d = 0; d < 4; ++d) {          // dense rows: lse over 8
            float tv[8];
#pragma unroll
            for (int j = 0; j < 8; ++j) tv[j] = sc[d * 8 + j] + col[j];
            float m = tv[0];
#pragma unroll
            for (int j = 1; j < 8; ++j) m = fmaxf(m, tv[j]);
            float ss = 0.0f;
#pragma unroll
            for (int j = 0; j < 8; ++j) ss += fexp2(tv[j] - m);
            nc[d] = m + flog2(ss);
        }
#pragma unroll
        for (int i = 0; i < 4; ++i) {          // sparse rows: logaddexp of 2
            const float a  = sc[32 + i] + col[i];
            const float bb = sc[36 + i] + col[i + 4];
            const float m  = fmaxf(a, bb);
            const float ss = fexp2(a - m) + fexp2(bb - m);
            nc[4 + i] = m + flog2(ss);
        }
#pragma unroll
        for (int j = 0; j < 8; ++j) col[j] = nc[j];
        yp += (size_t)N_DIM * C_DIM;
    }
    // store M[j][c] at cmat[((g*8 + c)*N_DIM + n)*8 + j]  (contig 8 per lane)
    float* __restrict__ op = cmat + (((size_t)g * 8 + c) * N_DIM + n) * 8;
#pragma unroll
    for (int j = 0; j < 8; ++j) op[j] = col[j];
}

// ---------------------------------------------------------------------------
// K3: per chain, fold the 64 chunk matrices into logZ via log-semiring
// mat-vec on an 8-vector starting at 0.
// ---------------------------------------------------------------------------
__global__ __launch_bounds__(256) void k3_combine(
    const float* __restrict__ cmat, float* __restrict__ corr)
{
    const int tid = threadIdx.x;
    const int d   = tid & 7;
    const int n   = blockIdx.x * 32 + (tid >> 3);

    float v[8];
#pragma unroll
    for (int j = 0; j < 8; ++j) v[j] = 0.0f;

#pragma unroll 1
    for (int g = 0; g < NCHUNK; ++g) {
        const float* mg = cmat + ((size_t)g * 8 * N_DIM + n) * 8 + d;
        float mm[8];
#pragma unroll
        for (int j = 0; j < 8; ++j) mm[j] = mg[(size_t)j * N_DIM * 8];
        float tv[8];
#pragma unroll
        for (int j = 0; j < 8; ++j) tv[j] = mm[j] + v[j];
        float m = tv[0];
#pragma unroll
        for (int j = 1; j < 8; ++j) m = fmaxf(m, tv[j]);
        float ss = 0.0f;
#pragma unroll
        for (int j = 0; j < 8; ++j) ss += fexp2(tv[j] - m);
        const float nv = m + flog2(ss);
#pragma unroll
        for (int j = 0; j < 8; ++j) v[j] = __shfl(nv, j, 8);
    }
    float m = v[0];
#pragma unroll
    for (int j = 1; j < 8; ++j) m = fmaxf(m, v[j]);
    float ss = 0.0f;
#pragma unroll
    for (int j = 0; j < 8; ++j) ss += fexp2(v[j] - m);
    const float lz2 = m + flog2(ss);                 // base-2 logZ
    if (d == 0) corr[n] = lz2 * LN2_F / (float)T_DIM;
}

// ---------------------------------------------------------------------------
// K4: out[t][n][c] = y[t][n][c] - corr[n]
// ---------------------------------------------------------------------------
__global__ __launch_bounds__(256) void k4_final(
    float* __restrict__ out, const float* __restrict__ corr)
{
    const unsigned int i = blockIdx.x * 256u + threadIdx.x;  // float4 index
    float4* o4 = (float4*)out;
    float4 v = o4[i];
    const unsigned int n = (i / 10u) & (N_DIM - 1);          // 10 float4 / row
    const float cr = corr[n];
    v.x -= cr; v.y -= cr; v.z -= cr; v.w -= cr;
    o4[i] = v;
}

// ---------------------------------------------------------------------------
extern "C" void kernel_launch(void* const* d_in, const int* in_sizes, int n_in,
                              void* d_out, int out_size, void* d_ws, size_t ws_size,
                              hipStream_t stream)
{
    const float* x = (const float*)d_in[0];
    const float* W = (const float*)d_in[1];
    const float* b = (const float*)d_in[2];
    float* y = (float*)d_out;

    float* cmat = (float*)d_ws;                               // 64*8*256*8 f32 = 4 MB
    float* corr = (float*)d_ws + (size_t)NCHUNK * 8 * N_DIM * 8;

    hipLaunchKernelGGL(k1_gemm_tanh, dim3(1024), dim3(256), 0, stream, x, W, b, y);
    hipLaunchKernelGGL(k2_chunks,    dim3(512),  dim3(256), 0, stream, y, cmat);
    hipLaunchKernelGGL(k3_combine,   dim3(8),    dim3(256), 0, stream, cmat, corr);
    hipLaunchKernelGGL(k4_final,     dim3((T_DIM * N_DIM * C_DIM / 4) / 256),
                       dim3(256), 0, stream, y, corr);
}